// Round 3
// baseline (322.518 us; speedup 1.0000x reference)
//
#include <hip/hip_runtime.h>

#define BQ_RADIUS2 0.25f
#define KK 32
#define NB 4
#define NP 8192
#define NS 2048
#define C1 32
#define C2 32
#define C3 64
#define EPSBN 1e-5f
#define RTOT 65536          /* S*K */
#define MTOT (NB*NS*KK)     /* 262144 */
#define NSLOT 32
#define NBLK 256            /* mega grid: 256 blocks x 1024 threads, 1 col/thread */

/* workspace offsets (in 4-byte elements).
   P1,P2,P3,BAR contiguous (8194 floats) — zeroed by k_pack every launch. */
#define OFF_G     0          /* 655360: packed [B][N][20] = xyz + 16 feat + pad */
#define OFF_IDX   655360     /* 262144 ints */
#define OFF_VALID 917504     /* 8192 ints */
#define OFF_P1    925696     /* 2048 = 32 slots * 2*C1 */
#define OFF_P2    927744     /* 2048 */
#define OFF_P3    929792     /* 4096 */
#define OFF_BAR   933888     /* 2 ints: cnt, gen */

/* ---- pack pc+feat into AoS g[B][N][20]; zero stat partials + barrier ---- */
__global__ __launch_bounds__(256) void k_pack(const float* __restrict__ pc,
                                              const float* __restrict__ feat,
                                              float* __restrict__ g,
                                              float* __restrict__ partials) {
  const int t = blockIdx.x * 256 + threadIdx.x;        /* 0..32767 */
  if (t < 8194) partials[t] = 0.f;                      /* zeros P1,P2,P3,BAR */
  const int b = t >> 13;
  const int j = t & (NP - 1);
  const float* pcb = pc + b * 3 * NP;
  float* gp = g + (size_t)t * 20;
  gp[0] = pcb[j];
  gp[1] = pcb[NP + j];
  gp[2] = pcb[2 * NP + j];
  const float* fb = feat + b * 16 * NP;
#pragma unroll
  for (int c = 0; c < 16; c++) gp[3 + c] = fb[c * NP + j];
  gp[19] = 0.f;
}

/* ---- ball query: one wave per query, 4 points/lane, early exit at K found ---- */
__global__ __launch_bounds__(256) void k_ballquery(const float* __restrict__ pc,
                                                   const float* __restrict__ newpc,
                                                   int* __restrict__ idx,
                                                   int* __restrict__ valid) {
  __shared__ int buf[4][KK];
  const int tid = threadIdx.x;
  const int w = tid >> 6, lane = tid & 63;
  const int gq = blockIdx.x * 4 + w;                    /* 0..8191 */
  const int b = gq >> 11, s = gq & (NS - 1);
  const float* np0 = newpc + b * 3 * NS;
  const float qx = np0[s], qy = np0[NS + s], qz = np0[2 * NS + s];
  const float* px = pc + b * 3 * NP;
  const float* py = px + NP;
  const float* pz = px + 2 * NP;
  if (lane == 0) buf[w][0] = 0;
  int cnt = 0;
  for (int j0 = 0; j0 < NP; j0 += 256) {
    const int jb = j0 + lane * 4;
    const float4 vx = *(const float4*)(px + jb);
    const float4 vy = *(const float4*)(py + jb);
    const float4 vz = *(const float4*)(pz + jb);
    int mm = 0;
    /* d2 with separate rounding, ((dx*dx + dy*dy) + dz*dz), to bit-match np f32 */
    {
      float dx = __fsub_rn(qx, vx.x), dy = __fsub_rn(qy, vy.x), dz = __fsub_rn(qz, vz.x);
      if (__fadd_rn(__fadd_rn(__fmul_rn(dx, dx), __fmul_rn(dy, dy)), __fmul_rn(dz, dz)) < BQ_RADIUS2) mm |= 1;
    }
    {
      float dx = __fsub_rn(qx, vx.y), dy = __fsub_rn(qy, vy.y), dz = __fsub_rn(qz, vz.y);
      if (__fadd_rn(__fadd_rn(__fmul_rn(dx, dx), __fmul_rn(dy, dy)), __fmul_rn(dz, dz)) < BQ_RADIUS2) mm |= 2;
    }
    {
      float dx = __fsub_rn(qx, vx.z), dy = __fsub_rn(qy, vy.z), dz = __fsub_rn(qz, vz.z);
      if (__fadd_rn(__fadd_rn(__fmul_rn(dx, dx), __fmul_rn(dy, dy)), __fmul_rn(dz, dz)) < BQ_RADIUS2) mm |= 4;
    }
    {
      float dx = __fsub_rn(qx, vx.w), dy = __fsub_rn(qy, vy.w), dz = __fsub_rn(qz, vz.w);
      if (__fadd_rn(__fadd_rn(__fmul_rn(dx, dx), __fmul_rn(dy, dy)), __fmul_rn(dz, dz)) < BQ_RADIUS2) mm |= 8;
    }
    const int c4 = __popc(mm);
    int pre = c4;                                       /* inclusive wave prefix-sum */
#pragma unroll
    for (int off = 1; off < 64; off <<= 1) {
      int v = __shfl_up(pre, off);
      if (lane >= off) pre += v;
    }
    const int total = __shfl(pre, 63);
    if (mm) {
      int base = cnt + pre - c4;
#pragma unroll
      for (int i = 0; i < 4; i++) {
        if ((mm >> i) & 1) {
          if (base < KK) buf[w][base] = jb + i;
          base++;
        }
      }
    }
    cnt += total;
    if (cnt >= KK) break;
  }
  __syncthreads();
  if (lane < KK) {
    const int f = cnt < KK ? cnt : KK;
    const int i0 = buf[w][0];                           /* 0 if cnt==0 */
    idx[gq * KK + lane] = (lane < f) ? buf[w][lane] : i0;
  }
  if (lane == 0) valid[gq] = (cnt > 0);
}

/* ---- software grid barrier (graph-capture-safe; all NBLK blocks are
   co-resident by construction: 1 block/CU max at 16 waves, 256 blocks). ---- */
__device__ __forceinline__ void gbar(int* bar, int tid) {
  __syncthreads();
  if (tid == 0) {
    __threadfence();                                    /* release stats atomics */
    int* gen = bar + 1;
    const int g = __hip_atomic_load(gen, __ATOMIC_ACQUIRE, __HIP_MEMORY_SCOPE_AGENT);
    const int a = __hip_atomic_fetch_add(bar, 1, __ATOMIC_ACQ_REL, __HIP_MEMORY_SCOPE_AGENT);
    if (a == NBLK - 1) {
      __hip_atomic_store(bar, 0, __ATOMIC_RELAXED, __HIP_MEMORY_SCOPE_AGENT);
      __hip_atomic_fetch_add(gen, 1, __ATOMIC_RELEASE, __HIP_MEMORY_SCOPE_AGENT);
    } else {
      while (__hip_atomic_load(gen, __ATOMIC_ACQUIRE, __HIP_MEMORY_SCOPE_AGENT) == g)
        __builtin_amdgcn_s_sleep(8);
    }
  }
  __syncthreads();
}

/* ---- block-level stats: 64-lane shuffle tree + cross-wave LDS + atomics ---- */
template <int C>
__device__ __forceinline__ void block_stats(const float* y, float (*red)[16],
                                            float* __restrict__ partial,
                                            int tid, int bid) {
  const int w = tid >> 6, lane = tid & 63;
#pragma unroll
  for (int c = 0; c < C; c++) {
    float a = y[c];
    float q = a * a;
    a += __shfl_xor(a, 1);  q += __shfl_xor(q, 1);
    a += __shfl_xor(a, 2);  q += __shfl_xor(q, 2);
    a += __shfl_xor(a, 4);  q += __shfl_xor(q, 4);
    a += __shfl_xor(a, 8);  q += __shfl_xor(q, 8);
    a += __shfl_xor(a, 16); q += __shfl_xor(q, 16);
    a += __shfl_xor(a, 32); q += __shfl_xor(q, 32);
    if (lane == 0) { red[c][w] = a; red[C + c][w] = q; }
  }
  __syncthreads();
  if (tid < 2 * C) {
    float v = 0.f;
#pragma unroll
    for (int ww = 0; ww < 16; ww++) v += red[tid][ww];
    atomicAdd(&partial[(bid & (NSLOT - 1)) * 2 * C + tid], v);
  }
}

/* ---- per-block reduction of 32 partial slots -> (scale, shift) in pl ---- */
template <int C>
__device__ __forceinline__ void bn_params(const float* __restrict__ partial,
                                          const float* __restrict__ gam,
                                          const float* __restrict__ bet,
                                          float* pl, float* tot, int tid) {
  if (tid < 2 * C) {
    float v = 0.f;
#pragma unroll 1
    for (int sl = 0; sl < NSLOT; ++sl) v += partial[sl * 2 * C + tid];
    tot[tid] = v;
  }
  __syncthreads();
  if (tid < C) {
    const float inv = 1.0f / (float)MTOT;
    const float mean = tot[tid] * inv;
    const float var = tot[C + tid] * inv - mean * mean;
    const float sc = gam[tid] * rsqrtf(var + EPSBN);
    pl[tid] = sc;
    pl[C + tid] = bet[tid] - mean * sc;
  }
  __syncthreads();
}

/* ---- fused gather + conv1/bn1 + conv2/bn2 + conv3/bn3 + mask. One column
   per thread, activations in registers, software barrier at 3 stats points.
   Weights read with wave-uniform indices -> scalar loads (K$), no LDS. ---- */
__global__ __launch_bounds__(1024, 4) void k_mega(
    const float* __restrict__ g, const int* __restrict__ idx,
    const float* __restrict__ newpc,
    const float* __restrict__ w1, const float* __restrict__ b1,
    const float* __restrict__ g1, const float* __restrict__ be1,
    const float* __restrict__ w2, const float* __restrict__ b2,
    const float* __restrict__ g2, const float* __restrict__ be2,
    const float* __restrict__ w3, const float* __restrict__ b3,
    const float* __restrict__ g3, const float* __restrict__ be3,
    const int* __restrict__ valid,
    float* __restrict__ p1, float* __restrict__ p2, float* __restrict__ p3,
    float* __restrict__ out, int* bar) {
  __shared__ float red[2 * C3][16];
  __shared__ float tot[2 * C3];
  __shared__ float pl[2 * C3];
  const int tid = threadIdx.x;
  const int bid = blockIdx.x;

  const int m = bid * 1024 + tid;                       /* column 0..262143 */
  const int b = m >> 16;
  const int r = m & (RTOT - 1);
  const int s = r >> 5;
  const int j = idx[m];
  const float* np0 = newpc + b * 3 * NS;

  /* gather: 20-float AoS row, subtract query center from xyz */
  float x[19];
  {
    const float4* gp = (const float4*)(g + (size_t)(b * NP + j) * 20);
    const float4 a0 = gp[0], a1 = gp[1], a2 = gp[2], a3 = gp[3], a4 = gp[4];
    x[0] = a0.x - np0[s]; x[1] = a0.y - np0[NS + s]; x[2] = a0.z - np0[2 * NS + s];
    x[3] = a0.w;
    x[4] = a1.x; x[5] = a1.y; x[6] = a1.z; x[7] = a1.w;
    x[8] = a2.x; x[9] = a2.y; x[10] = a2.z; x[11] = a2.w;
    x[12] = a3.x; x[13] = a3.y; x[14] = a3.z; x[15] = a3.w;
    x[16] = a4.x; x[17] = a4.y; x[18] = a4.z;
  }

  /* conv1: 19 -> 32 */
  float y1[C1];
#pragma unroll
  for (int o = 0; o < C1; o++) {
    float acc = b1[o];
    const float* wr = w1 + o * 19;
#pragma unroll
    for (int c = 0; c < 19; c++) acc = fmaf(wr[c], x[c], acc);
    y1[o] = acc;
  }
  block_stats<C1>(y1, red, p1, tid, bid);
  gbar(bar, tid);

  /* bn1 + relu + conv2: 32 -> 32 */
  bn_params<C1>(p1, g1, be1, pl, tot, tid);
#pragma unroll
  for (int c = 0; c < C1; c++) y1[c] = fmaxf(fmaf(y1[c], pl[c], pl[C1 + c]), 0.f);
  float y2[C2];
#pragma unroll
  for (int o = 0; o < C2; o++) {
    float acc = b2[o];
    const float* wr = w2 + o * C1;
#pragma unroll
    for (int c = 0; c < C1; c++) acc = fmaf(wr[c], y1[c], acc);
    y2[o] = acc;
  }
  block_stats<C2>(y2, red, p2, tid, bid);
  gbar(bar, tid);

  /* bn2 + relu + conv3: 32 -> 64 */
  bn_params<C2>(p2, g2, be2, pl, tot, tid);
#pragma unroll
  for (int c = 0; c < C2; c++) y2[c] = fmaxf(fmaf(y2[c], pl[c], pl[C2 + c]), 0.f);
  float y3[C3];
#pragma unroll
  for (int o = 0; o < C3; o++) {
    float acc = b3[o];
    const float* wr = w3 + o * C2;
#pragma unroll
    for (int c = 0; c < C2; c++) acc = fmaf(wr[c], y2[c], acc);
    y3[o] = acc;
  }
  block_stats<C3>(y3, red, p3, tid, bid);
  gbar(bar, tid);

  /* bn3 + relu + validity mask + store (coalesced 4B/lane, 64 channels) */
  bn_params<C3>(p3, g3, be3, pl, tot, tid);
  const float mval = valid[(b << 11) + s] ? 1.f : 0.f;
  float* ob = out + ((size_t)b * C3) * RTOT + r;
#pragma unroll
  for (int o = 0; o < C3; o++)
    ob[(size_t)o * RTOT] = fmaxf(fmaf(y3[o], pl[o], pl[C3 + o]), 0.f) * mval;
}

extern "C" void kernel_launch(void* const* d_in, const int* in_sizes, int n_in,
                              void* d_out, int out_size, void* d_ws, size_t ws_size,
                              hipStream_t stream) {
  const float* pc    = (const float*)d_in[0];
  const float* feat  = (const float*)d_in[1];
  const float* newpc = (const float*)d_in[2];
  const float* w1 = (const float*)d_in[3];
  const float* b1 = (const float*)d_in[4];
  const float* g1 = (const float*)d_in[5];
  const float* be1 = (const float*)d_in[6];
  const float* w2 = (const float*)d_in[7];
  const float* b2 = (const float*)d_in[8];
  const float* g2 = (const float*)d_in[9];
  const float* be2 = (const float*)d_in[10];
  const float* w3 = (const float*)d_in[11];
  const float* b3 = (const float*)d_in[12];
  const float* g3 = (const float*)d_in[13];
  const float* be3 = (const float*)d_in[14];

  float* ws = (float*)d_ws;
  float* gbuf  = ws + OFF_G;
  int*   idx   = (int*)(ws + OFF_IDX);
  int*   valid = (int*)(ws + OFF_VALID);
  float* p1 = ws + OFF_P1;
  float* p2 = ws + OFF_P2;
  float* p3 = ws + OFF_P3;
  int*   bar = (int*)(ws + OFF_BAR);
  float* out = (float*)d_out;

  k_pack<<<dim3(128), dim3(256), 0, stream>>>(pc, feat, gbuf, p1);
  k_ballquery<<<dim3(2048), dim3(256), 0, stream>>>(pc, newpc, idx, valid);
  k_mega<<<dim3(NBLK), dim3(1024), 0, stream>>>(
      gbuf, idx, newpc, w1, b1, g1, be1, w2, b2, g2, be2, w3, b3, g3, be3,
      valid, p1, p2, p3, out, bar);
}

// Round 4
// 307.509 us; speedup vs baseline: 1.0488x; 1.0488x over previous
//
#include <hip/hip_runtime.h>

#define BQ_RADIUS2 0.25f
#define KK 32
#define NB 4
#define NP 8192
#define NS 2048
#define C1 32
#define C2 32
#define C3 64
#define EPSBN 1e-5f
#define RTOT 65536          /* S*K */
#define MTOT (NB*NS*KK)     /* 262144 */
#define NSLOT 32
#define NBLK 256            /* mega grid: 256 blocks x 1024 threads, 1 col/thread */

/* workspace offsets (in 4-byte elements).
   P1,P2,P3,BAR contiguous (8194 floats) — zeroed by k_pack every launch. */
#define OFF_G     0          /* 655360: packed [B][N][20] = xyz + 16 feat + pad */
#define OFF_IDX   655360     /* 262144 ints */
#define OFF_VALID 917504     /* 8192 ints */
#define OFF_P1    925696     /* 2048 = 32 slots * 2*C1 */
#define OFF_P2    927744     /* 2048 */
#define OFF_P3    929792     /* 4096 */
#define OFF_BAR   933888     /* 2 ints: cnt, gen */
#define OFF_PAR3  933952     /* 128 floats */

/* ---- pack pc+feat into AoS g[B][N][20]; zero stat partials + barrier ---- */
__global__ __launch_bounds__(256) void k_pack(const float* __restrict__ pc,
                                              const float* __restrict__ feat,
                                              float* __restrict__ g,
                                              float* __restrict__ partials) {
  const int t = blockIdx.x * 256 + threadIdx.x;        /* 0..32767 */
  if (t < 8194) partials[t] = 0.f;                      /* zeros P1,P2,P3,BAR */
  const int b = t >> 13;
  const int j = t & (NP - 1);
  const float* pcb = pc + b * 3 * NP;
  float* gp = g + (size_t)t * 20;
  gp[0] = pcb[j];
  gp[1] = pcb[NP + j];
  gp[2] = pcb[2 * NP + j];
  const float* fb = feat + b * 16 * NP;
#pragma unroll
  for (int c = 0; c < 16; c++) gp[3 + c] = fb[c * NP + j];
  gp[19] = 0.f;
}

/* ---- ball query: one wave per query, 4 points/lane, early exit at K found ---- */
__global__ __launch_bounds__(256) void k_ballquery(const float* __restrict__ pc,
                                                   const float* __restrict__ newpc,
                                                   int* __restrict__ idx,
                                                   int* __restrict__ valid) {
  __shared__ int buf[4][KK];
  const int tid = threadIdx.x;
  const int w = tid >> 6, lane = tid & 63;
  const int gq = blockIdx.x * 4 + w;                    /* 0..8191 */
  const int b = gq >> 11, s = gq & (NS - 1);
  const float* np0 = newpc + b * 3 * NS;
  const float qx = np0[s], qy = np0[NS + s], qz = np0[2 * NS + s];
  const float* px = pc + b * 3 * NP;
  const float* py = px + NP;
  const float* pz = px + 2 * NP;
  if (lane == 0) buf[w][0] = 0;
  int cnt = 0;
  for (int j0 = 0; j0 < NP; j0 += 256) {
    const int jb = j0 + lane * 4;
    const float4 vx = *(const float4*)(px + jb);
    const float4 vy = *(const float4*)(py + jb);
    const float4 vz = *(const float4*)(pz + jb);
    int mm = 0;
    /* d2 with separate rounding, ((dx*dx + dy*dy) + dz*dz), to bit-match np f32 */
    {
      float dx = __fsub_rn(qx, vx.x), dy = __fsub_rn(qy, vy.x), dz = __fsub_rn(qz, vz.x);
      if (__fadd_rn(__fadd_rn(__fmul_rn(dx, dx), __fmul_rn(dy, dy)), __fmul_rn(dz, dz)) < BQ_RADIUS2) mm |= 1;
    }
    {
      float dx = __fsub_rn(qx, vx.y), dy = __fsub_rn(qy, vy.y), dz = __fsub_rn(qz, vz.y);
      if (__fadd_rn(__fadd_rn(__fmul_rn(dx, dx), __fmul_rn(dy, dy)), __fmul_rn(dz, dz)) < BQ_RADIUS2) mm |= 2;
    }
    {
      float dx = __fsub_rn(qx, vx.z), dy = __fsub_rn(qy, vy.z), dz = __fsub_rn(qz, vz.z);
      if (__fadd_rn(__fadd_rn(__fmul_rn(dx, dx), __fmul_rn(dy, dy)), __fmul_rn(dz, dz)) < BQ_RADIUS2) mm |= 4;
    }
    {
      float dx = __fsub_rn(qx, vx.w), dy = __fsub_rn(qy, vy.w), dz = __fsub_rn(qz, vz.w);
      if (__fadd_rn(__fadd_rn(__fmul_rn(dx, dx), __fmul_rn(dy, dy)), __fmul_rn(dz, dz)) < BQ_RADIUS2) mm |= 8;
    }
    const int c4 = __popc(mm);
    int pre = c4;                                       /* inclusive wave prefix-sum */
#pragma unroll
    for (int off = 1; off < 64; off <<= 1) {
      int v = __shfl_up(pre, off);
      if (lane >= off) pre += v;
    }
    const int total = __shfl(pre, 63);
    if (mm) {
      int base = cnt + pre - c4;
#pragma unroll
      for (int i = 0; i < 4; i++) {
        if ((mm >> i) & 1) {
          if (base < KK) buf[w][base] = jb + i;
          base++;
        }
      }
    }
    cnt += total;
    if (cnt >= KK) break;
  }
  __syncthreads();
  if (lane < KK) {
    const int f = cnt < KK ? cnt : KK;
    const int i0 = buf[w][0];                           /* 0 if cnt==0 */
    idx[gq * KK + lane] = (lane < f) ? buf[w][lane] : i0;
  }
  if (lane == 0) valid[gq] = (cnt > 0);
}

/* ---- software grid barrier (graph-capture-safe; all NBLK blocks are
   co-resident by construction: 1024-thr block = 16 waves = whole CU,
   256 blocks <= 256 CUs). ---- */
__device__ __forceinline__ void gbar(int* bar, int tid) {
  __syncthreads();
  if (tid == 0) {
    __threadfence();                                    /* release stats atomics */
    int* gen = bar + 1;
    const int g = __hip_atomic_load(gen, __ATOMIC_ACQUIRE, __HIP_MEMORY_SCOPE_AGENT);
    const int a = __hip_atomic_fetch_add(bar, 1, __ATOMIC_ACQ_REL, __HIP_MEMORY_SCOPE_AGENT);
    if (a == NBLK - 1) {
      __hip_atomic_store(bar, 0, __ATOMIC_RELAXED, __HIP_MEMORY_SCOPE_AGENT);
      __hip_atomic_fetch_add(gen, 1, __ATOMIC_RELEASE, __HIP_MEMORY_SCOPE_AGENT);
    } else {
      while (__hip_atomic_load(gen, __ATOMIC_ACQUIRE, __HIP_MEMORY_SCOPE_AGENT) == g)
        __builtin_amdgcn_s_sleep(8);
    }
  }
  __syncthreads();
}

/* inline per-channel stat reduce: 64-lane shuffle tree, wave leads -> LDS.
   No register array ever escapes through a pointer (SROA-safe). */
#define STAT_REDUCE(ACC, O, C) { \
    float a_ = (ACC), q_ = (ACC) * (ACC); \
    a_ += __shfl_xor(a_, 1);  q_ += __shfl_xor(q_, 1); \
    a_ += __shfl_xor(a_, 2);  q_ += __shfl_xor(q_, 2); \
    a_ += __shfl_xor(a_, 4);  q_ += __shfl_xor(q_, 4); \
    a_ += __shfl_xor(a_, 8);  q_ += __shfl_xor(q_, 8); \
    a_ += __shfl_xor(a_, 16); q_ += __shfl_xor(q_, 16); \
    a_ += __shfl_xor(a_, 32); q_ += __shfl_xor(q_, 32); \
    if (lane == 0) { red[(O)][w] = a_; red[(C) + (O)][w] = q_; } }

/* ---- cross-wave flush of red[2C][16] into the global partial slots ---- */
template <int C>
__device__ __forceinline__ void flush_stats(float (*red)[16],
                                            float* __restrict__ partial,
                                            int tid, int bid) {
  __syncthreads();
  if (tid < 2 * C) {
    float v = 0.f;
#pragma unroll
    for (int ww = 0; ww < 16; ww++) v += red[tid][ww];
    atomicAdd(&partial[(bid & (NSLOT - 1)) * 2 * C + tid], v);
  }
}

/* ---- per-block reduction of 32 partial slots -> (scale, shift) in pl ---- */
template <int C>
__device__ __forceinline__ void bn_params(const float* __restrict__ partial,
                                          const float* __restrict__ gam,
                                          const float* __restrict__ bet,
                                          float* pl, float* tot, int tid) {
  if (tid < 2 * C) {
    float v = 0.f;
#pragma unroll 1
    for (int sl = 0; sl < NSLOT; ++sl) v += partial[sl * 2 * C + tid];
    tot[tid] = v;
  }
  __syncthreads();
  if (tid < C) {
    const float inv = 1.0f / (float)MTOT;
    const float mean = tot[tid] * inv;
    const float var = tot[C + tid] * inv - mean * mean;
    const float sc = gam[tid] * rsqrtf(var + EPSBN);
    pl[tid] = sc;
    pl[C + tid] = bet[tid] - mean * sc;
  }
  __syncthreads();
}

/* ---- fused gather + conv1/bn1 + conv2/bn2 + conv3(streamed, raw store).
   One column per thread; y1,y2 in registers (peak live ~90 < 128 VGPR cap);
   conv3 output is never materialized — per-channel acc is stat-reduced and
   stored raw; bn3+relu+mask applied by k_final. ---- */
__global__ __launch_bounds__(1024, 4) void k_mega(
    const float* __restrict__ g, const int* __restrict__ idx,
    const float* __restrict__ newpc,
    const float* __restrict__ w1, const float* __restrict__ b1,
    const float* __restrict__ g1, const float* __restrict__ be1,
    const float* __restrict__ w2, const float* __restrict__ b2,
    const float* __restrict__ g2, const float* __restrict__ be2,
    const float* __restrict__ w3, const float* __restrict__ b3,
    float* __restrict__ p1, float* __restrict__ p2, float* __restrict__ p3,
    float* __restrict__ out, int* bar) {
  __shared__ float red[2 * C3][16];
  __shared__ float tot[2 * C3];
  __shared__ float pl[2 * C3];
  const int tid = threadIdx.x;
  const int bid = blockIdx.x;
  const int w = tid >> 6, lane = tid & 63;

  const int m = bid * 1024 + tid;                       /* column 0..262143 */
  const int b = m >> 16;
  const int r = m & (RTOT - 1);
  const int s = r >> 5;
  const int j = idx[m];
  const float* np0 = newpc + b * 3 * NS;

  /* gather: 20-float AoS row, subtract query center from xyz */
  float x[19];
  {
    const float4* gp = (const float4*)(g + (size_t)(b * NP + j) * 20);
    const float4 a0 = gp[0], a1 = gp[1], a2 = gp[2], a3 = gp[3], a4 = gp[4];
    x[0] = a0.x - np0[s]; x[1] = a0.y - np0[NS + s]; x[2] = a0.z - np0[2 * NS + s];
    x[3] = a0.w;
    x[4] = a1.x; x[5] = a1.y; x[6] = a1.z; x[7] = a1.w;
    x[8] = a2.x; x[9] = a2.y; x[10] = a2.z; x[11] = a2.w;
    x[12] = a3.x; x[13] = a3.y; x[14] = a3.z; x[15] = a3.w;
    x[16] = a4.x; x[17] = a4.y; x[18] = a4.z;
  }

  /* conv1: 19 -> 32, stats inline */
  float y1[C1];
#pragma unroll
  for (int o = 0; o < C1; o++) {
    float acc = b1[o];
    const float* wr = w1 + o * 19;
#pragma unroll
    for (int c = 0; c < 19; c++) acc = fmaf(wr[c], x[c], acc);
    y1[o] = acc;
    STAT_REDUCE(acc, o, C1)
  }
  flush_stats<C1>(red, p1, tid, bid);
  gbar(bar, tid);

  /* bn1 + relu + conv2: 32 -> 32, stats inline */
  bn_params<C1>(p1, g1, be1, pl, tot, tid);
#pragma unroll
  for (int c = 0; c < C1; c++) y1[c] = fmaxf(fmaf(y1[c], pl[c], pl[C1 + c]), 0.f);
  float y2[C2];
#pragma unroll
  for (int o = 0; o < C2; o++) {
    float acc = b2[o];
    const float* wr = w2 + o * C1;
#pragma unroll
    for (int c = 0; c < C1; c++) acc = fmaf(wr[c], y1[c], acc);
    y2[o] = acc;
    STAT_REDUCE(acc, o, C2)
  }
  flush_stats<C2>(red, p2, tid, bid);
  gbar(bar, tid);

  /* bn2 + relu + conv3: 32 -> 64, streamed raw store, stats inline */
  bn_params<C2>(p2, g2, be2, pl, tot, tid);
#pragma unroll
  for (int c = 0; c < C2; c++) y2[c] = fmaxf(fmaf(y2[c], pl[c], pl[C2 + c]), 0.f);
  float* ob = out + ((size_t)b * C3) * RTOT + r;
#pragma unroll
  for (int o = 0; o < C3; o++) {
    float acc = b3[o];
    const float* wr = w3 + o * C2;
#pragma unroll
    for (int c = 0; c < C2; c++) acc = fmaf(wr[c], y2[c], acc);
    ob[(size_t)o * RTOT] = acc;                         /* raw pre-BN */
    STAT_REDUCE(acc, o, C3)
  }
  flush_stats<C3>(red, p3, tid, bid);
}

/* ---- finalize BN params for layer 3 ---- */
__global__ void k_params(const float* __restrict__ partial,
                         const float* __restrict__ gamma,
                         const float* __restrict__ beta,
                         float* __restrict__ params, int C) {
  __shared__ float tot[2 * C3];
  const int t = threadIdx.x;                 /* blockDim == 2C */
  float v = 0.f;
#pragma unroll 1
  for (int sl = 0; sl < NSLOT; ++sl) v += partial[sl * 2 * C + t];
  tot[t] = v;
  __syncthreads();
  if (t < C) {
    const float inv = 1.0f / (float)MTOT;
    const float mean = tot[t] * inv;
    const float ex2 = tot[C + t] * inv;
    const float var = ex2 - mean * mean;
    const float sc = gamma[t] * rsqrtf(var + EPSBN);
    params[t] = sc;
    params[C + t] = beta[t] - mean * sc;
  }
}

/* ---- bn3 + relu + validity mask, in-place on d_out ---- */
__global__ __launch_bounds__(256) void k_final(float* __restrict__ out,
                                               const float* __restrict__ par,
                                               const int* __restrict__ valid) {
  const int t = blockIdx.x * 256 + threadIdx.x;   /* float4 per thread */
  const size_t e = (size_t)t * 4;
  const int b = t >> 20;
  const int o = (t >> 14) & 63;
  const int s = (t & 16383) >> 3;
  const float sc = par[o], sh = par[C3 + o];
  const float m = valid[(b << 11) + s] ? 1.f : 0.f;
  float4 v = *(float4*)(out + e);
  v.x = fmaxf(fmaf(v.x, sc, sh), 0.f) * m;
  v.y = fmaxf(fmaf(v.y, sc, sh), 0.f) * m;
  v.z = fmaxf(fmaf(v.z, sc, sh), 0.f) * m;
  v.w = fmaxf(fmaf(v.w, sc, sh), 0.f) * m;
  *(float4*)(out + e) = v;
}

extern "C" void kernel_launch(void* const* d_in, const int* in_sizes, int n_in,
                              void* d_out, int out_size, void* d_ws, size_t ws_size,
                              hipStream_t stream) {
  const float* pc    = (const float*)d_in[0];
  const float* feat  = (const float*)d_in[1];
  const float* newpc = (const float*)d_in[2];
  const float* w1 = (const float*)d_in[3];
  const float* b1 = (const float*)d_in[4];
  const float* g1 = (const float*)d_in[5];
  const float* be1 = (const float*)d_in[6];
  const float* w2 = (const float*)d_in[7];
  const float* b2 = (const float*)d_in[8];
  const float* g2 = (const float*)d_in[9];
  const float* be2 = (const float*)d_in[10];
  const float* w3 = (const float*)d_in[11];
  const float* b3 = (const float*)d_in[12];
  const float* g3 = (const float*)d_in[13];
  const float* be3 = (const float*)d_in[14];

  float* ws = (float*)d_ws;
  float* gbuf  = ws + OFF_G;
  int*   idx   = (int*)(ws + OFF_IDX);
  int*   valid = (int*)(ws + OFF_VALID);
  float* p1 = ws + OFF_P1;
  float* p2 = ws + OFF_P2;
  float* p3 = ws + OFF_P3;
  int*   bar = (int*)(ws + OFF_BAR);
  float* par3 = ws + OFF_PAR3;
  float* out = (float*)d_out;

  k_pack<<<dim3(128), dim3(256), 0, stream>>>(pc, feat, gbuf, p1);
  k_ballquery<<<dim3(2048), dim3(256), 0, stream>>>(pc, newpc, idx, valid);
  k_mega<<<dim3(NBLK), dim3(1024), 0, stream>>>(
      gbuf, idx, newpc, w1, b1, g1, be1, w2, b2, g2, be2, w3, b3,
      p1, p2, p3, out, bar);
  k_params<<<dim3(1), dim3(2 * C3), 0, stream>>>(p3, g3, be3, par3, C3);
  k_final<<<dim3(16384), dim3(256), 0, stream>>>(out, par3, valid);
}

// Round 6
// 272.952 us; speedup vs baseline: 1.1816x; 1.1266x over previous
//
#include <hip/hip_runtime.h>

#define BQ_RADIUS2 0.25f
#define KK 32
#define NB 4
#define NP 8192
#define NS 2048
#define C1 32
#define C2 32
#define C3 64
#define EPSBN 1e-5f
#define RTOT 65536          /* S*K */
#define MTOT (NB*NS*KK)     /* 262144 */
#define NSLOT 32

/* workspace offsets (in 4-byte elements).
   P1,P2,P3 contiguous (8192 floats) — zeroed by k_pack every launch. */
#define OFF_G     0          /* 655360: packed [B][N][20] = xyz + 16 feat + pad */
#define OFF_IDX   655360     /* 262144 ints */
#define OFF_VALID 917504     /* 8192 ints */
#define OFF_P1    925696     /* 2048 = 32 slots * 2*C1 */
#define OFF_P2    927744     /* 2048 */
#define OFF_P3    929792     /* 4096 */
#define OFF_PAR3  933888     /* 128 floats */

/* ---- pack pc+feat into AoS g[B][N][20]; zero stat partials ---- */
__global__ __launch_bounds__(256) void k_pack(const float* __restrict__ pc,
                                              const float* __restrict__ feat,
                                              float* __restrict__ g,
                                              float* __restrict__ partials) {
  const int t = blockIdx.x * 256 + threadIdx.x;        /* 0..32767 */
  if (t < 8192) partials[t] = 0.f;                      /* zeros P1,P2,P3 */
  const int b = t >> 13;
  const int j = t & (NP - 1);
  const float* pcb = pc + b * 3 * NP;
  float* gp = g + (size_t)t * 20;
  gp[0] = pcb[j];
  gp[1] = pcb[NP + j];
  gp[2] = pcb[2 * NP + j];
  const float* fb = feat + b * 16 * NP;
#pragma unroll
  for (int c = 0; c < 16; c++) gp[3 + c] = fb[c * NP + j];
  gp[19] = 0.f;
}

/* ---- ball query: one wave per query, 4 points/lane, early exit at K found ---- */
__global__ __launch_bounds__(256) void k_ballquery(const float* __restrict__ pc,
                                                   const float* __restrict__ newpc,
                                                   int* __restrict__ idx,
                                                   int* __restrict__ valid) {
  __shared__ int buf[4][KK];
  const int tid = threadIdx.x;
  const int w = tid >> 6, lane = tid & 63;
  const int gq = blockIdx.x * 4 + w;                    /* 0..8191 */
  const int b = gq >> 11, s = gq & (NS - 1);
  const float* np0 = newpc + b * 3 * NS;
  const float qx = np0[s], qy = np0[NS + s], qz = np0[2 * NS + s];
  const float* px = pc + b * 3 * NP;
  const float* py = px + NP;
  const float* pz = px + 2 * NP;
  if (lane == 0) buf[w][0] = 0;
  int cnt = 0;
  for (int j0 = 0; j0 < NP; j0 += 256) {
    const int jb = j0 + lane * 4;
    const float4 vx = *(const float4*)(px + jb);
    const float4 vy = *(const float4*)(py + jb);
    const float4 vz = *(const float4*)(pz + jb);
    int mm = 0;
    /* d2 with separate rounding, ((dx*dx + dy*dy) + dz*dz), to bit-match np f32 */
    {
      float dx = __fsub_rn(qx, vx.x), dy = __fsub_rn(qy, vy.x), dz = __fsub_rn(qz, vz.x);
      if (__fadd_rn(__fadd_rn(__fmul_rn(dx, dx), __fmul_rn(dy, dy)), __fmul_rn(dz, dz)) < BQ_RADIUS2) mm |= 1;
    }
    {
      float dx = __fsub_rn(qx, vx.y), dy = __fsub_rn(qy, vy.y), dz = __fsub_rn(qz, vz.y);
      if (__fadd_rn(__fadd_rn(__fmul_rn(dx, dx), __fmul_rn(dy, dy)), __fmul_rn(dz, dz)) < BQ_RADIUS2) mm |= 2;
    }
    {
      float dx = __fsub_rn(qx, vx.z), dy = __fsub_rn(qy, vy.z), dz = __fsub_rn(qz, vz.z);
      if (__fadd_rn(__fadd_rn(__fmul_rn(dx, dx), __fmul_rn(dy, dy)), __fmul_rn(dz, dz)) < BQ_RADIUS2) mm |= 4;
    }
    {
      float dx = __fsub_rn(qx, vx.w), dy = __fsub_rn(qy, vy.w), dz = __fsub_rn(qz, vz.w);
      if (__fadd_rn(__fadd_rn(__fmul_rn(dx, dx), __fmul_rn(dy, dy)), __fmul_rn(dz, dz)) < BQ_RADIUS2) mm |= 8;
    }
    const int c4 = __popc(mm);
    int pre = c4;                                       /* inclusive wave prefix-sum */
#pragma unroll
    for (int off = 1; off < 64; off <<= 1) {
      int v = __shfl_up(pre, off);
      if (lane >= off) pre += v;
    }
    const int total = __shfl(pre, 63);
    if (mm) {
      int base = cnt + pre - c4;
#pragma unroll
      for (int i = 0; i < 4; i++) {
        if ((mm >> i) & 1) {
          if (base < KK) buf[w][base] = jb + i;
          base++;
        }
      }
    }
    cnt += total;
    if (cnt >= KK) break;
  }
  __syncthreads();
  if (lane < KK) {
    const int f = cnt < KK ? cnt : KK;
    const int i0 = buf[w][0];                           /* 0 if cnt==0 */
    idx[gq * KK + lane] = (lane < f) ? buf[w][lane] : i0;
  }
  if (lane == 0) valid[gq] = (cnt > 0);
}

/* inline per-channel stat reduce: 64-lane shuffle tree, wave leads -> LDS */
#define STAT_REDUCE(ACC, O, C) { \
    float a_ = (ACC), q_ = (ACC) * (ACC); \
    a_ += __shfl_xor(a_, 1);  q_ += __shfl_xor(q_, 1); \
    a_ += __shfl_xor(a_, 2);  q_ += __shfl_xor(q_, 2); \
    a_ += __shfl_xor(a_, 4);  q_ += __shfl_xor(q_, 4); \
    a_ += __shfl_xor(a_, 8);  q_ += __shfl_xor(q_, 8); \
    a_ += __shfl_xor(a_, 16); q_ += __shfl_xor(q_, 16); \
    a_ += __shfl_xor(a_, 32); q_ += __shfl_xor(q_, 32); \
    if (lane == 0) { red[(O)][w] = a_; red[(C) + (O)][w] = q_; } }

/* cross-wave flush of red[2C][4] into the global partial slots */
#define FLUSH_STATS(C, PARTIAL) { \
    __syncthreads(); \
    if (tid < 2 * (C)) { \
      const float v_ = (red[tid][0] + red[tid][1]) + (red[tid][2] + red[tid][3]); \
      atomicAdd(&(PARTIAL)[(blockIdx.x & (NSLOT - 1)) * 2 * (C) + tid], v_); \
    } }

/* per-block reduction of 32 partial slots -> (scale, shift) in pl[2C] */
#define BN_PARAMS(C, PARTIAL, GAM, BET) { \
    if (tid < 2 * (C)) { \
      float v_ = 0.f; \
      _Pragma("unroll 1") \
      for (int sl_ = 0; sl_ < NSLOT; ++sl_) v_ += (PARTIAL)[sl_ * 2 * (C) + tid]; \
      tot[tid] = v_; \
    } \
    __syncthreads(); \
    if (tid < (C)) { \
      const float inv_ = 1.0f / (float)MTOT; \
      const float mean_ = tot[tid] * inv_; \
      const float var_ = tot[(C) + tid] * inv_ - mean_ * mean_; \
      const float sc_ = (GAM)[tid] * rsqrtf(var_ + EPSBN); \
      pl[tid] = sc_; \
      pl[(C) + tid] = (BET)[tid] - mean_ * sc_; \
    } \
    __syncthreads(); }

/* ---- gather + conv1 (19->32), one column/thread, 1024 blocks ---- */
__global__ __launch_bounds__(256, 4) void k_conv1(const float* __restrict__ g,
                                                  const int* __restrict__ idx,
                                                  const float* __restrict__ newpc,
                                                  const float* __restrict__ w1,
                                                  const float* __restrict__ b1,
                                                  float* __restrict__ y,
                                                  float* __restrict__ partial) {
  __shared__ float red[2 * C1][4];
  const int tid = threadIdx.x;
  const int w = tid >> 6, lane = tid & 63;
  const int m = blockIdx.x * 256 + tid;                 /* column 0..262143 */
  const int b = m >> 16;
  const int r = m & (RTOT - 1);
  const int s = r >> 5;
  const int j = idx[m];
  const float* np0 = newpc + b * 3 * NS;

  float x[19];
  {
    const float4* gp = (const float4*)(g + (size_t)(b * NP + j) * 20);
    const float4 a0 = gp[0], a1 = gp[1], a2 = gp[2], a3 = gp[3], a4 = gp[4];
    x[0] = a0.x - np0[s]; x[1] = a0.y - np0[NS + s]; x[2] = a0.z - np0[2 * NS + s];
    x[3] = a0.w;
    x[4] = a1.x; x[5] = a1.y; x[6] = a1.z; x[7] = a1.w;
    x[8] = a2.x; x[9] = a2.y; x[10] = a2.z; x[11] = a2.w;
    x[12] = a3.x; x[13] = a3.y; x[14] = a3.z; x[15] = a3.w;
    x[16] = a4.x; x[17] = a4.y; x[18] = a4.z;
  }
  float* yb = y + ((size_t)b * C3) * RTOT + r;
#pragma unroll 4
  for (int o = 0; o < C1; o++) {
    float acc = b1[o];                                  /* uniform -> s_load */
    const float* wr = w1 + o * 19;
#pragma unroll
    for (int c = 0; c < 19; c++) acc = fmaf(wr[c], x[c], acc);
    yb[(size_t)o * RTOT] = acc;
    STAT_REDUCE(acc, o, C1)
  }
  FLUSH_STATS(C1, partial)
}

/* ---- bn1 params (folded) + bn1+relu + conv2 (32->32) in-place ---- */
__global__ __launch_bounds__(256, 4) void k_conv2(const float* __restrict__ w2,
                                                  const float* __restrict__ b2,
                                                  const float* __restrict__ p1,
                                                  const float* __restrict__ g1,
                                                  const float* __restrict__ be1,
                                                  float* y,
                                                  float* __restrict__ partial) {
  __shared__ float red[2 * C2][4];
  __shared__ float tot[2 * C1];
  __shared__ float pl[2 * C1];
  const int tid = threadIdx.x;
  const int w = tid >> 6, lane = tid & 63;
  BN_PARAMS(C1, p1, g1, be1)
  const int m = blockIdx.x * 256 + tid;
  const int b = m >> 16;
  const int r = m & (RTOT - 1);
  float* yb = y + ((size_t)b * C3) * RTOT + r;
  float xr[C1];
#pragma unroll
  for (int c = 0; c < C1; c++) {
    const float v = yb[(size_t)c * RTOT];
    xr[c] = fmaxf(fmaf(v, pl[c], pl[C1 + c]), 0.f);
  }
#pragma unroll 4
  for (int o = 0; o < C2; o++) {
    float acc = b2[o];
    const float* wr = w2 + o * C1;
#pragma unroll
    for (int c = 0; c < C1; c++) acc = fmaf(wr[c], xr[c], acc);
    yb[(size_t)o * RTOT] = acc;                         /* thread owns column: race-free */
    STAT_REDUCE(acc, o, C2)
  }
  FLUSH_STATS(C2, partial)
}

/* ---- bn2 params (folded) + bn2+relu + conv3 (32->64) in-place ---- */
__global__ __launch_bounds__(256, 4) void k_conv3(const float* __restrict__ w3,
                                                  const float* __restrict__ b3,
                                                  const float* __restrict__ p2,
                                                  const float* __restrict__ g2,
                                                  const float* __restrict__ be2,
                                                  float* y,
                                                  float* __restrict__ partial) {
  __shared__ float red[2 * C3][4];
  __shared__ float tot[2 * C2];
  __shared__ float pl[2 * C2];
  const int tid = threadIdx.x;
  const int w = tid >> 6, lane = tid & 63;
  BN_PARAMS(C2, p2, g2, be2)
  const int m = blockIdx.x * 256 + tid;
  const int b = m >> 16;
  const int r = m & (RTOT - 1);
  float* yb = y + ((size_t)b * C3) * RTOT + r;
  float xr[C2];
#pragma unroll
  for (int c = 0; c < C2; c++) {
    const float v = yb[(size_t)c * RTOT];
    xr[c] = fmaxf(fmaf(v, pl[c], pl[C2 + c]), 0.f);
  }
#pragma unroll 4
  for (int o = 0; o < C3; o++) {
    float acc = b3[o];
    const float* wr = w3 + o * C2;
#pragma unroll
    for (int c = 0; c < C2; c++) acc = fmaf(wr[c], xr[c], acc);
    yb[(size_t)o * RTOT] = acc;                         /* raw pre-BN */
    STAT_REDUCE(acc, o, C3)
  }
  FLUSH_STATS(C3, partial)
}

/* ---- finalize BN params for layer 3 ---- */
__global__ void k_params(const float* __restrict__ partial,
                         const float* __restrict__ gamma,
                         const float* __restrict__ beta,
                         float* __restrict__ params, int C) {
  __shared__ float tot[2 * C3];
  const int t = threadIdx.x;                 /* blockDim == 2C */
  float v = 0.f;
#pragma unroll 1
  for (int sl = 0; sl < NSLOT; ++sl) v += partial[sl * 2 * C + t];
  tot[t] = v;
  __syncthreads();
  if (t < C) {
    const float inv = 1.0f / (float)MTOT;
    const float mean = tot[t] * inv;
    const float ex2 = tot[C + t] * inv;
    const float var = ex2 - mean * mean;
    const float sc = gamma[t] * rsqrtf(var + EPSBN);
    params[t] = sc;
    params[C + t] = beta[t] - mean * sc;
  }
}

/* ---- bn3 + relu + validity mask, in-place on d_out ---- */
__global__ __launch_bounds__(256) void k_final(float* __restrict__ out,
                                               const float* __restrict__ par,
                                               const int* __restrict__ valid) {
  const int t = blockIdx.x * 256 + threadIdx.x;   /* float4 per thread */
  const size_t e = (size_t)t * 4;
  const int b = t >> 20;
  const int o = (t >> 14) & 63;
  const int s = (t & 16383) >> 3;
  const float sc = par[o], sh = par[C3 + o];
  const float m = valid[(b << 11) + s] ? 1.f : 0.f;
  float4 v = *(float4*)(out + e);
  v.x = fmaxf(fmaf(v.x, sc, sh), 0.f) * m;
  v.y = fmaxf(fmaf(v.y, sc, sh), 0.f) * m;
  v.z = fmaxf(fmaf(v.z, sc, sh), 0.f) * m;
  v.w = fmaxf(fmaf(v.w, sc, sh), 0.f) * m;
  *(float4*)(out + e) = v;
}

extern "C" void kernel_launch(void* const* d_in, const int* in_sizes, int n_in,
                              void* d_out, int out_size, void* d_ws, size_t ws_size,
                              hipStream_t stream) {
  const float* pc    = (const float*)d_in[0];
  const float* feat  = (const float*)d_in[1];
  const float* newpc = (const float*)d_in[2];
  const float* w1 = (const float*)d_in[3];
  const float* b1 = (const float*)d_in[4];
  const float* g1 = (const float*)d_in[5];
  const float* be1 = (const float*)d_in[6];
  const float* w2 = (const float*)d_in[7];
  const float* b2 = (const float*)d_in[8];
  const float* g2 = (const float*)d_in[9];
  const float* be2 = (const float*)d_in[10];
  const float* w3 = (const float*)d_in[11];
  const float* b3 = (const float*)d_in[12];
  const float* g3 = (const float*)d_in[13];
  const float* be3 = (const float*)d_in[14];

  float* ws = (float*)d_ws;
  float* gbuf  = ws + OFF_G;
  int*   idx   = (int*)(ws + OFF_IDX);
  int*   valid = (int*)(ws + OFF_VALID);
  float* p1 = ws + OFF_P1;
  float* p2 = ws + OFF_P2;
  float* p3 = ws + OFF_P3;
  float* par3 = ws + OFF_PAR3;
  float* out = (float*)d_out;

  k_pack<<<dim3(128), dim3(256), 0, stream>>>(pc, feat, gbuf, p1);
  k_ballquery<<<dim3(2048), dim3(256), 0, stream>>>(pc, newpc, idx, valid);
  k_conv1<<<dim3(1024), dim3(256), 0, stream>>>(gbuf, idx, newpc, w1, b1, out, p1);
  k_conv2<<<dim3(1024), dim3(256), 0, stream>>>(w2, b2, p1, g1, be1, out, p2);
  k_conv3<<<dim3(1024), dim3(256), 0, stream>>>(w3, b3, p2, g2, be2, out, p3);
  k_params<<<dim3(1), dim3(2 * C3), 0, stream>>>(p3, g3, be3, par3, C3);
  k_final<<<dim3(16384), dim3(256), 0, stream>>>(out, par3, valid);
}

// Round 7
// 270.970 us; speedup vs baseline: 1.1902x; 1.0073x over previous
//
#include <hip/hip_runtime.h>

#define BQ_RADIUS2 0.25f
#define KK 32
#define NB 4
#define NP 8192
#define NS 2048
#define C1 32
#define C2 32
#define C3 64
#define EPSBN 1e-5f
#define RTOT 65536          /* S*K */
#define MTOT (NB*NS*KK)     /* 262144 */
#define NSLOT 32

/* workspace offsets (in 4-byte elements).
   P1,P2,P3 contiguous (8192 floats) — zeroed by k_pack every launch. */
#define OFF_G     0          /* 655360: packed [B][N][20] = xyz + 16 feat + pad */
#define OFF_IDX   655360     /* 262144 ints */
#define OFF_VALID 917504     /* 8192 ints */
#define OFF_P1    925696     /* 2048 = 32 slots * 2*C1 */
#define OFF_P2    927744     /* 2048 */
#define OFF_P3    929792     /* 4096 */
#define OFF_PAR3  933888     /* 128 floats */

/* ---- pack pc+feat into AoS g[B][N][20]; zero stat partials ---- */
__global__ __launch_bounds__(256) void k_pack(const float* __restrict__ pc,
                                              const float* __restrict__ feat,
                                              float* __restrict__ g,
                                              float* __restrict__ partials) {
  const int t = blockIdx.x * 256 + threadIdx.x;        /* 0..32767 */
  if (t < 8192) partials[t] = 0.f;                      /* zeros P1,P2,P3 */
  const int b = t >> 13;
  const int j = t & (NP - 1);
  const float* pcb = pc + b * 3 * NP;
  float* gp = g + (size_t)t * 20;
  gp[0] = pcb[j];
  gp[1] = pcb[NP + j];
  gp[2] = pcb[2 * NP + j];
  const float* fb = feat + b * 16 * NP;
#pragma unroll
  for (int c = 0; c < 16; c++) gp[3 + c] = fb[c * NP + j];
  gp[19] = 0.f;
}

/* ---- ball query: one wave per query, 4 points/lane, early exit at K found ---- */
__global__ __launch_bounds__(256) void k_ballquery(const float* __restrict__ pc,
                                                   const float* __restrict__ newpc,
                                                   int* __restrict__ idx,
                                                   int* __restrict__ valid) {
  __shared__ int buf[4][KK];
  const int tid = threadIdx.x;
  const int w = tid >> 6, lane = tid & 63;
  const int gq = blockIdx.x * 4 + w;                    /* 0..8191 */
  const int b = gq >> 11, s = gq & (NS - 1);
  const float* np0 = newpc + b * 3 * NS;
  const float qx = np0[s], qy = np0[NS + s], qz = np0[2 * NS + s];
  const float* px = pc + b * 3 * NP;
  const float* py = px + NP;
  const float* pz = px + 2 * NP;
  if (lane == 0) buf[w][0] = 0;
  int cnt = 0;
  for (int j0 = 0; j0 < NP; j0 += 256) {
    const int jb = j0 + lane * 4;
    const float4 vx = *(const float4*)(px + jb);
    const float4 vy = *(const float4*)(py + jb);
    const float4 vz = *(const float4*)(pz + jb);
    int mm = 0;
    /* d2 with separate rounding, ((dx*dx + dy*dy) + dz*dz), to bit-match np f32 */
    {
      float dx = __fsub_rn(qx, vx.x), dy = __fsub_rn(qy, vy.x), dz = __fsub_rn(qz, vz.x);
      if (__fadd_rn(__fadd_rn(__fmul_rn(dx, dx), __fmul_rn(dy, dy)), __fmul_rn(dz, dz)) < BQ_RADIUS2) mm |= 1;
    }
    {
      float dx = __fsub_rn(qx, vx.y), dy = __fsub_rn(qy, vy.y), dz = __fsub_rn(qz, vz.y);
      if (__fadd_rn(__fadd_rn(__fmul_rn(dx, dx), __fmul_rn(dy, dy)), __fmul_rn(dz, dz)) < BQ_RADIUS2) mm |= 2;
    }
    {
      float dx = __fsub_rn(qx, vx.z), dy = __fsub_rn(qy, vy.z), dz = __fsub_rn(qz, vz.z);
      if (__fadd_rn(__fadd_rn(__fmul_rn(dx, dx), __fmul_rn(dy, dy)), __fmul_rn(dz, dz)) < BQ_RADIUS2) mm |= 4;
    }
    {
      float dx = __fsub_rn(qx, vx.w), dy = __fsub_rn(qy, vy.w), dz = __fsub_rn(qz, vz.w);
      if (__fadd_rn(__fadd_rn(__fmul_rn(dx, dx), __fmul_rn(dy, dy)), __fmul_rn(dz, dz)) < BQ_RADIUS2) mm |= 8;
    }
    const int c4 = __popc(mm);
    int pre = c4;                                       /* inclusive wave prefix-sum */
#pragma unroll
    for (int off = 1; off < 64; off <<= 1) {
      int v = __shfl_up(pre, off);
      if (lane >= off) pre += v;
    }
    const int total = __shfl(pre, 63);
    if (mm) {
      int base = cnt + pre - c4;
#pragma unroll
      for (int i = 0; i < 4; i++) {
        if ((mm >> i) & 1) {
          if (base < KK) buf[w][base] = jb + i;
          base++;
        }
      }
    }
    cnt += total;
    if (cnt >= KK) break;
  }
  __syncthreads();
  if (lane < KK) {
    const int f = cnt < KK ? cnt : KK;
    const int i0 = buf[w][0];                           /* 0 if cnt==0 */
    idx[gq * KK + lane] = (lane < f) ? buf[w][lane] : i0;
  }
  if (lane == 0) valid[gq] = (cnt > 0);
}

/* inline per-channel stat reduce: 64-lane shuffle tree, wave leads -> LDS */
#define STAT_REDUCE(ACC, O, C) { \
    float a_ = (ACC), q_ = (ACC) * (ACC); \
    a_ += __shfl_xor(a_, 1);  q_ += __shfl_xor(q_, 1); \
    a_ += __shfl_xor(a_, 2);  q_ += __shfl_xor(q_, 2); \
    a_ += __shfl_xor(a_, 4);  q_ += __shfl_xor(q_, 4); \
    a_ += __shfl_xor(a_, 8);  q_ += __shfl_xor(q_, 8); \
    a_ += __shfl_xor(a_, 16); q_ += __shfl_xor(q_, 16); \
    a_ += __shfl_xor(a_, 32); q_ += __shfl_xor(q_, 32); \
    if (lane == 0) { red[(O)][w] = a_; red[(C) + (O)][w] = q_; } }

/* cross-wave flush of red[2C][4] into the global partial slots */
#define FLUSH_STATS(C, PARTIAL) { \
    __syncthreads(); \
    if (tid < 2 * (C)) { \
      const float v_ = (red[tid][0] + red[tid][1]) + (red[tid][2] + red[tid][3]); \
      atomicAdd(&(PARTIAL)[(blockIdx.x & (NSLOT - 1)) * 2 * (C) + tid], v_); \
    } }

/* per-block reduction of 32 partial slots -> (scale, shift) in pl[2C] */
#define BN_PARAMS(C, PARTIAL, GAM, BET) { \
    if (tid < 2 * (C)) { \
      float v_ = 0.f; \
      _Pragma("unroll 1") \
      for (int sl_ = 0; sl_ < NSLOT; ++sl_) v_ += (PARTIAL)[sl_ * 2 * (C) + tid]; \
      tot[tid] = v_; \
    } \
    __syncthreads(); \
    if (tid < (C)) { \
      const float inv_ = 1.0f / (float)MTOT; \
      const float mean_ = tot[tid] * inv_; \
      const float var_ = tot[(C) + tid] * inv_ - mean_ * mean_; \
      const float sc_ = (GAM)[tid] * rsqrtf(var_ + EPSBN); \
      pl[tid] = sc_; \
      pl[(C) + tid] = (BET)[tid] - mean_ * sc_; \
    } \
    __syncthreads(); }

/* 4 sequential fmas of weight row WP[K..K+3] against float4 V, into T */
#define FMA4(WP, K, V, T) { \
    T = fmaf((WP)[(K)    ], (V).x, T); \
    T = fmaf((WP)[(K) + 1], (V).y, T); \
    T = fmaf((WP)[(K) + 2], (V).z, T); \
    T = fmaf((WP)[(K) + 3], (V).w, T); }

/* load 4 consecutive channels (stride RTOT) + bn(scale pl[.], shift pl[32+.]) + relu
   into named float4 X — no arrays, nothing for the compiler to demote. */
#define LDBN4(X, C0) { \
    X.x = fmaxf(fmaf(yb[(size_t)((C0)    ) * RTOT], pl[(C0)    ], pl[32 + (C0)    ]), 0.f); \
    X.y = fmaxf(fmaf(yb[(size_t)((C0) + 1) * RTOT], pl[(C0) + 1], pl[32 + (C0) + 1]), 0.f); \
    X.z = fmaxf(fmaf(yb[(size_t)((C0) + 2) * RTOT], pl[(C0) + 2], pl[32 + (C0) + 2]), 0.f); \
    X.w = fmaxf(fmaf(yb[(size_t)((C0) + 3) * RTOT], pl[(C0) + 3], pl[32 + (C0) + 3]), 0.f); }

/* ---- gather + conv1 (19->32), one column/thread, 1024 blocks ---- */
__global__ __launch_bounds__(256) void k_conv1(const float* __restrict__ g,
                                               const int* __restrict__ idx,
                                               const float* __restrict__ newpc,
                                               const float* __restrict__ w1,
                                               const float* __restrict__ b1,
                                               float* __restrict__ y,
                                               float* __restrict__ partial) {
  __shared__ float red[2 * C1][4];
  const int tid = threadIdx.x;
  const int w = tid >> 6, lane = tid & 63;
  const int m = blockIdx.x * 256 + tid;                 /* column 0..262143 */
  const int b = m >> 16;
  const int r = m & (RTOT - 1);
  const int s = r >> 5;
  const int j = idx[m];
  const float* np0 = newpc + b * 3 * NS;

  const float4* gp = (const float4*)(g + (size_t)(b * NP + j) * 20);
  float4 a0 = gp[0];
  const float4 a1 = gp[1], a2 = gp[2], a3 = gp[3], a4 = gp[4];
  a0.x -= np0[s]; a0.y -= np0[NS + s]; a0.z -= np0[2 * NS + s];

  float* yb = y + ((size_t)b * C3) * RTOT + r;
#pragma unroll 4
  for (int o = 0; o < C1; o++) {
    const float* wr = w1 + o * 19;                      /* uniform -> s_load */
    float acc = b1[o];
    FMA4(wr, 0, a0, acc)
    FMA4(wr, 4, a1, acc)
    FMA4(wr, 8, a2, acc)
    FMA4(wr, 12, a3, acc)
    acc = fmaf(wr[16], a4.x, acc);
    acc = fmaf(wr[17], a4.y, acc);
    acc = fmaf(wr[18], a4.z, acc);
    yb[(size_t)o * RTOT] = acc;
    STAT_REDUCE(acc, o, C1)
  }
  FLUSH_STATS(C1, partial)
}

/* ---- bn1 params (folded) + bn1+relu + conv2 (32->32) in-place ---- */
__global__ __launch_bounds__(256) void k_conv2(const float* __restrict__ w2,
                                               const float* __restrict__ b2,
                                               const float* __restrict__ p1,
                                               const float* __restrict__ g1,
                                               const float* __restrict__ be1,
                                               float* y,
                                               float* __restrict__ partial) {
  __shared__ float red[2 * C2][4];
  __shared__ float tot[2 * C1];
  __shared__ float pl[2 * C1];
  const int tid = threadIdx.x;
  const int w = tid >> 6, lane = tid & 63;
  BN_PARAMS(C1, p1, g1, be1)
  const int m = blockIdx.x * 256 + tid;
  const int b = m >> 16;
  const int r = m & (RTOT - 1);
  float* yb = y + ((size_t)b * C3) * RTOT + r;
  float4 x0, x1, x2, x3, x4, x5, x6, x7;                /* named, no arrays */
  LDBN4(x0, 0)  LDBN4(x1, 4)  LDBN4(x2, 8)  LDBN4(x3, 12)
  LDBN4(x4, 16) LDBN4(x5, 20) LDBN4(x6, 24) LDBN4(x7, 28)
#pragma unroll 4
  for (int o = 0; o < C2; o++) {
    const float* wr = w2 + o * C1;                      /* uniform -> s_load */
    float acc = b2[o];
    FMA4(wr, 0, x0, acc)
    FMA4(wr, 4, x1, acc)
    FMA4(wr, 8, x2, acc)
    FMA4(wr, 12, x3, acc)
    FMA4(wr, 16, x4, acc)
    FMA4(wr, 20, x5, acc)
    FMA4(wr, 24, x6, acc)
    FMA4(wr, 28, x7, acc)
    yb[(size_t)o * RTOT] = acc;                         /* thread owns column: race-free */
    STAT_REDUCE(acc, o, C2)
  }
  FLUSH_STATS(C2, partial)
}

/* ---- bn2 params (folded) + bn2+relu + conv3 (32->64) in-place ---- */
__global__ __launch_bounds__(256) void k_conv3(const float* __restrict__ w3,
                                               const float* __restrict__ b3,
                                               const float* __restrict__ p2,
                                               const float* __restrict__ g2,
                                               const float* __restrict__ be2,
                                               float* y,
                                               float* __restrict__ partial) {
  __shared__ float red[2 * C3][4];
  __shared__ float tot[2 * C2];
  __shared__ float pl[2 * C2];
  const int tid = threadIdx.x;
  const int w = tid >> 6, lane = tid & 63;
  BN_PARAMS(C2, p2, g2, be2)
  const int m = blockIdx.x * 256 + tid;
  const int b = m >> 16;
  const int r = m & (RTOT - 1);
  float* yb = y + ((size_t)b * C3) * RTOT + r;
  float4 x0, x1, x2, x3, x4, x5, x6, x7;
  LDBN4(x0, 0)  LDBN4(x1, 4)  LDBN4(x2, 8)  LDBN4(x3, 12)
  LDBN4(x4, 16) LDBN4(x5, 20) LDBN4(x6, 24) LDBN4(x7, 28)
#pragma unroll 4
  for (int o = 0; o < C3; o++) {
    const float* wr = w3 + o * C2;
    float acc = b3[o];
    FMA4(wr, 0, x0, acc)
    FMA4(wr, 4, x1, acc)
    FMA4(wr, 8, x2, acc)
    FMA4(wr, 12, x3, acc)
    FMA4(wr, 16, x4, acc)
    FMA4(wr, 20, x5, acc)
    FMA4(wr, 24, x6, acc)
    FMA4(wr, 28, x7, acc)
    yb[(size_t)o * RTOT] = acc;                         /* raw pre-BN */
    STAT_REDUCE(acc, o, C3)
  }
  FLUSH_STATS(C3, partial)
}

/* ---- finalize BN params for layer 3 ---- */
__global__ void k_params(const float* __restrict__ partial,
                         const float* __restrict__ gamma,
                         const float* __restrict__ beta,
                         float* __restrict__ params, int C) {
  __shared__ float tot[2 * C3];
  const int t = threadIdx.x;                 /* blockDim == 2C */
  float v = 0.f;
#pragma unroll 1
  for (int sl = 0; sl < NSLOT; ++sl) v += partial[sl * 2 * C + t];
  tot[t] = v;
  __syncthreads();
  if (t < C) {
    const float inv = 1.0f / (float)MTOT;
    const float mean = tot[t] * inv;
    const float ex2 = tot[C + t] * inv;
    const float var = ex2 - mean * mean;
    const float sc = gamma[t] * rsqrtf(var + EPSBN);
    params[t] = sc;
    params[C + t] = beta[t] - mean * sc;
  }
}

/* ---- bn3 + relu + validity mask, in-place on d_out ---- */
__global__ __launch_bounds__(256) void k_final(float* __restrict__ out,
                                               const float* __restrict__ par,
                                               const int* __restrict__ valid) {
  const int t = blockIdx.x * 256 + threadIdx.x;   /* float4 per thread */
  const size_t e = (size_t)t * 4;
  const int b = t >> 20;
  const int o = (t >> 14) & 63;
  const int s = (t & 16383) >> 3;
  const float sc = par[o], sh = par[C3 + o];
  const float m = valid[(b << 11) + s] ? 1.f : 0.f;
  float4 v = *(float4*)(out + e);
  v.x = fmaxf(fmaf(v.x, sc, sh), 0.f) * m;
  v.y = fmaxf(fmaf(v.y, sc, sh), 0.f) * m;
  v.z = fmaxf(fmaf(v.z, sc, sh), 0.f) * m;
  v.w = fmaxf(fmaf(v.w, sc, sh), 0.f) * m;
  *(float4*)(out + e) = v;
}

extern "C" void kernel_launch(void* const* d_in, const int* in_sizes, int n_in,
                              void* d_out, int out_size, void* d_ws, size_t ws_size,
                              hipStream_t stream) {
  const float* pc    = (const float*)d_in[0];
  const float* feat  = (const float*)d_in[1];
  const float* newpc = (const float*)d_in[2];
  const float* w1 = (const float*)d_in[3];
  const float* b1 = (const float*)d_in[4];
  const float* g1 = (const float*)d_in[5];
  const float* be1 = (const float*)d_in[6];
  const float* w2 = (const float*)d_in[7];
  const float* b2 = (const float*)d_in[8];
  const float* g2 = (const float*)d_in[9];
  const float* be2 = (const float*)d_in[10];
  const float* w3 = (const float*)d_in[11];
  const float* b3 = (const float*)d_in[12];
  const float* g3 = (const float*)d_in[13];
  const float* be3 = (const float*)d_in[14];

  float* ws = (float*)d_ws;
  float* gbuf  = ws + OFF_G;
  int*   idx   = (int*)(ws + OFF_IDX);
  int*   valid = (int*)(ws + OFF_VALID);
  float* p1 = ws + OFF_P1;
  float* p2 = ws + OFF_P2;
  float* p3 = ws + OFF_P3;
  float* par3 = ws + OFF_PAR3;
  float* out = (float*)d_out;

  k_pack<<<dim3(128), dim3(256), 0, stream>>>(pc, feat, gbuf, p1);
  k_ballquery<<<dim3(2048), dim3(256), 0, stream>>>(pc, newpc, idx, valid);
  k_conv1<<<dim3(1024), dim3(256), 0, stream>>>(gbuf, idx, newpc, w1, b1, out, p1);
  k_conv2<<<dim3(1024), dim3(256), 0, stream>>>(w2, b2, p1, g1, be1, out, p2);
  k_conv3<<<dim3(1024), dim3(256), 0, stream>>>(w3, b3, p2, g2, be2, out, p3);
  k_params<<<dim3(1), dim3(2 * C3), 0, stream>>>(p3, g3, be3, par3, C3);
  k_final<<<dim3(16384), dim3(256), 0, stream>>>(out, par3, valid);
}

// Round 8
// 270.244 us; speedup vs baseline: 1.1934x; 1.0027x over previous
//
#include <hip/hip_runtime.h>

#define BQ_RADIUS2 0.25f
#define KK 32
#define NB 4
#define NP 8192
#define NS 2048
#define C1 32
#define C2 32
#define C3 64
#define EPSBN 1e-5f
#define RTOT 65536          /* S*K */
#define MTOT (NB*NS*KK)     /* 262144 */
#define NSLOT 32

/* workspace offsets (in 4-byte elements).
   P1,P2,P3 contiguous (8192 floats) — zeroed by k_pack every launch. */
#define OFF_G     0          /* 655360: packed [B][N][20] = xyz + 16 feat + pad */
#define OFF_IDX   655360     /* 262144 ints */
#define OFF_VALID 917504     /* 8192 ints */
#define OFF_P1    925696     /* 2048 = 32 slots * 2*C1 */
#define OFF_P2    927744     /* 2048 */
#define OFF_P3    929792     /* 4096 */
#define OFF_PAR3  933888     /* 128 floats */

/* ---- pack pc+feat into AoS g[B][N][20]; zero stat partials ---- */
__global__ __launch_bounds__(256) void k_pack(const float* __restrict__ pc,
                                              const float* __restrict__ feat,
                                              float* __restrict__ g,
                                              float* __restrict__ partials) {
  const int t = blockIdx.x * 256 + threadIdx.x;        /* 0..32767 */
  if (t < 8192) partials[t] = 0.f;                      /* zeros P1,P2,P3 */
  const int b = t >> 13;
  const int j = t & (NP - 1);
  const float* pcb = pc + b * 3 * NP;
  float* gp = g + (size_t)t * 20;
  gp[0] = pcb[j];
  gp[1] = pcb[NP + j];
  gp[2] = pcb[2 * NP + j];
  const float* fb = feat + b * 16 * NP;
#pragma unroll
  for (int c = 0; c < 16; c++) gp[3 + c] = fb[c * NP + j];
  gp[19] = 0.f;
}

/* ---- ball query: one wave per query, 4 points/lane, early exit at K found ---- */
__global__ __launch_bounds__(256) void k_ballquery(const float* __restrict__ pc,
                                                   const float* __restrict__ newpc,
                                                   int* __restrict__ idx,
                                                   int* __restrict__ valid) {
  __shared__ int buf[4][KK];
  const int tid = threadIdx.x;
  const int w = tid >> 6, lane = tid & 63;
  const int gq = blockIdx.x * 4 + w;                    /* 0..8191 */
  const int b = gq >> 11, s = gq & (NS - 1);
  const float* np0 = newpc + b * 3 * NS;
  const float qx = np0[s], qy = np0[NS + s], qz = np0[2 * NS + s];
  const float* px = pc + b * 3 * NP;
  const float* py = px + NP;
  const float* pz = px + 2 * NP;
  if (lane == 0) buf[w][0] = 0;
  int cnt = 0;
  for (int j0 = 0; j0 < NP; j0 += 256) {
    const int jb = j0 + lane * 4;
    const float4 vx = *(const float4*)(px + jb);
    const float4 vy = *(const float4*)(py + jb);
    const float4 vz = *(const float4*)(pz + jb);
    int mm = 0;
    /* d2 with separate rounding, ((dx*dx + dy*dy) + dz*dz), to bit-match np f32 */
    {
      float dx = __fsub_rn(qx, vx.x), dy = __fsub_rn(qy, vy.x), dz = __fsub_rn(qz, vz.x);
      if (__fadd_rn(__fadd_rn(__fmul_rn(dx, dx), __fmul_rn(dy, dy)), __fmul_rn(dz, dz)) < BQ_RADIUS2) mm |= 1;
    }
    {
      float dx = __fsub_rn(qx, vx.y), dy = __fsub_rn(qy, vy.y), dz = __fsub_rn(qz, vz.y);
      if (__fadd_rn(__fadd_rn(__fmul_rn(dx, dx), __fmul_rn(dy, dy)), __fmul_rn(dz, dz)) < BQ_RADIUS2) mm |= 2;
    }
    {
      float dx = __fsub_rn(qx, vx.z), dy = __fsub_rn(qy, vy.z), dz = __fsub_rn(qz, vz.z);
      if (__fadd_rn(__fadd_rn(__fmul_rn(dx, dx), __fmul_rn(dy, dy)), __fmul_rn(dz, dz)) < BQ_RADIUS2) mm |= 4;
    }
    {
      float dx = __fsub_rn(qx, vx.w), dy = __fsub_rn(qy, vy.w), dz = __fsub_rn(qz, vz.w);
      if (__fadd_rn(__fadd_rn(__fmul_rn(dx, dx), __fmul_rn(dy, dy)), __fmul_rn(dz, dz)) < BQ_RADIUS2) mm |= 8;
    }
    const int c4 = __popc(mm);
    int pre = c4;                                       /* inclusive wave prefix-sum */
#pragma unroll
    for (int off = 1; off < 64; off <<= 1) {
      int v = __shfl_up(pre, off);
      if (lane >= off) pre += v;
    }
    const int total = __shfl(pre, 63);
    if (mm) {
      int base = cnt + pre - c4;
#pragma unroll
      for (int i = 0; i < 4; i++) {
        if ((mm >> i) & 1) {
          if (base < KK) buf[w][base] = jb + i;
          base++;
        }
      }
    }
    cnt += total;
    if (cnt >= KK) break;
  }
  __syncthreads();
  if (lane < KK) {
    const int f = cnt < KK ? cnt : KK;
    const int i0 = buf[w][0];                           /* 0 if cnt==0 */
    idx[gq * KK + lane] = (lane < f) ? buf[w][lane] : i0;
  }
  if (lane == 0) valid[gq] = (cnt > 0);
}

/* inline per-channel stat reduce: 64-lane shuffle tree, wave leads -> LDS */
#define STAT_REDUCE(ACC, O, C) { \
    float a_ = (ACC), q_ = (ACC) * (ACC); \
    a_ += __shfl_xor(a_, 1);  q_ += __shfl_xor(q_, 1); \
    a_ += __shfl_xor(a_, 2);  q_ += __shfl_xor(q_, 2); \
    a_ += __shfl_xor(a_, 4);  q_ += __shfl_xor(q_, 4); \
    a_ += __shfl_xor(a_, 8);  q_ += __shfl_xor(q_, 8); \
    a_ += __shfl_xor(a_, 16); q_ += __shfl_xor(q_, 16); \
    a_ += __shfl_xor(a_, 32); q_ += __shfl_xor(q_, 32); \
    if (lane == 0) { red[(O)][w] = a_; red[(C) + (O)][w] = q_; } }

/* cross-wave flush of red[2C][4] into the global partial slots */
#define FLUSH_STATS(C, PARTIAL) { \
    __syncthreads(); \
    if (tid < 2 * (C)) { \
      const float v_ = (red[tid][0] + red[tid][1]) + (red[tid][2] + red[tid][3]); \
      atomicAdd(&(PARTIAL)[(blockIdx.x & (NSLOT - 1)) * 2 * (C) + tid], v_); \
    } }

/* per-block reduction of 32 partial slots -> (scale, shift) in pl[2C] */
#define BN_PARAMS(C, PARTIAL, GAM, BET) { \
    if (tid < 2 * (C)) { \
      float v_ = 0.f; \
      _Pragma("unroll 1") \
      for (int sl_ = 0; sl_ < NSLOT; ++sl_) v_ += (PARTIAL)[sl_ * 2 * (C) + tid]; \
      tot[tid] = v_; \
    } \
    __syncthreads(); \
    if (tid < (C)) { \
      const float inv_ = 1.0f / (float)MTOT; \
      const float mean_ = tot[tid] * inv_; \
      const float var_ = tot[(C) + tid] * inv_ - mean_ * mean_; \
      const float sc_ = (GAM)[tid] * rsqrtf(var_ + EPSBN); \
      pl[tid] = sc_; \
      pl[(C) + tid] = (BET)[tid] - mean_ * sc_; \
    } \
    __syncthreads(); }

/* 4 sequential fmas of weight row WP[K..K+3] against float4 V, into T */
#define FMA4(WP, K, V, T) { \
    T = fmaf((WP)[(K)    ], (V).x, T); \
    T = fmaf((WP)[(K) + 1], (V).y, T); \
    T = fmaf((WP)[(K) + 2], (V).z, T); \
    T = fmaf((WP)[(K) + 3], (V).w, T); }

/* load 4 consecutive channels (stride RTOT) + bn + relu into named float4 X */
#define LDBN4(X, C0) { \
    X.x = fmaxf(fmaf(yb[(size_t)((C0)    ) * RTOT], pl[(C0)    ], pl[32 + (C0)    ]), 0.f); \
    X.y = fmaxf(fmaf(yb[(size_t)((C0) + 1) * RTOT], pl[(C0) + 1], pl[32 + (C0) + 1]), 0.f); \
    X.z = fmaxf(fmaf(yb[(size_t)((C0) + 2) * RTOT], pl[(C0) + 2], pl[32 + (C0) + 2]), 0.f); \
    X.w = fmaxf(fmaf(yb[(size_t)((C0) + 3) * RTOT], pl[(C0) + 3], pl[32 + (C0) + 3]), 0.f); }

/* ---- gather + conv1 (19->32), one column/thread, 1024 blocks.
   __launch_bounds__(256, 2): min-waves=2 relaxes the VGPR allocator
   (1/2 -> ~104 VGPR in registers; 4/default -> spill to 32, rounds 6/7). ---- */
__global__ __launch_bounds__(256, 2) void k_conv1(const float* __restrict__ g,
                                                  const int* __restrict__ idx,
                                                  const float* __restrict__ newpc,
                                                  const float* __restrict__ w1,
                                                  const float* __restrict__ b1,
                                                  float* __restrict__ y,
                                                  float* __restrict__ partial) {
  __shared__ float red[2 * C1][4];
  const int tid = threadIdx.x;
  const int w = tid >> 6, lane = tid & 63;
  const int m = blockIdx.x * 256 + tid;                 /* column 0..262143 */
  const int b = m >> 16;
  const int r = m & (RTOT - 1);
  const int s = r >> 5;
  const int j = idx[m];
  const float* np0 = newpc + b * 3 * NS;

  const float4* gp = (const float4*)(g + (size_t)(b * NP + j) * 20);
  float4 a0 = gp[0];
  const float4 a1 = gp[1], a2 = gp[2], a3 = gp[3], a4 = gp[4];
  a0.x -= np0[s]; a0.y -= np0[NS + s]; a0.z -= np0[2 * NS + s];

  float* yb = y + ((size_t)b * C3) * RTOT + r;
#pragma unroll 4
  for (int o = 0; o < C1; o++) {
    const float* wr = w1 + o * 19;                      /* uniform -> s_load */
    float acc = b1[o];
    FMA4(wr, 0, a0, acc)
    FMA4(wr, 4, a1, acc)
    FMA4(wr, 8, a2, acc)
    FMA4(wr, 12, a3, acc)
    acc = fmaf(wr[16], a4.x, acc);
    acc = fmaf(wr[17], a4.y, acc);
    acc = fmaf(wr[18], a4.z, acc);
    yb[(size_t)o * RTOT] = acc;
    STAT_REDUCE(acc, o, C1)
  }
  FLUSH_STATS(C1, partial)
}

/* ---- bn1 params (folded) + bn1+relu + conv2 (32->32) in-place ---- */
__global__ __launch_bounds__(256, 2) void k_conv2(const float* __restrict__ w2,
                                                  const float* __restrict__ b2,
                                                  const float* __restrict__ p1,
                                                  const float* __restrict__ g1,
                                                  const float* __restrict__ be1,
                                                  float* y,
                                                  float* __restrict__ partial) {
  __shared__ float red[2 * C2][4];
  __shared__ float tot[2 * C1];
  __shared__ float pl[2 * C1];
  const int tid = threadIdx.x;
  const int w = tid >> 6, lane = tid & 63;
  BN_PARAMS(C1, p1, g1, be1)
  const int m = blockIdx.x * 256 + tid;
  const int b = m >> 16;
  const int r = m & (RTOT - 1);
  float* yb = y + ((size_t)b * C3) * RTOT + r;
  float4 x0, x1, x2, x3, x4, x5, x6, x7;                /* named, no arrays */
  LDBN4(x0, 0)  LDBN4(x1, 4)  LDBN4(x2, 8)  LDBN4(x3, 12)
  LDBN4(x4, 16) LDBN4(x5, 20) LDBN4(x6, 24) LDBN4(x7, 28)
#pragma unroll 4
  for (int o = 0; o < C2; o++) {
    const float* wr = w2 + o * C1;                      /* uniform -> s_load */
    float acc = b2[o];
    FMA4(wr, 0, x0, acc)
    FMA4(wr, 4, x1, acc)
    FMA4(wr, 8, x2, acc)
    FMA4(wr, 12, x3, acc)
    FMA4(wr, 16, x4, acc)
    FMA4(wr, 20, x5, acc)
    FMA4(wr, 24, x6, acc)
    FMA4(wr, 28, x7, acc)
    yb[(size_t)o * RTOT] = acc;                         /* thread owns column: race-free */
    STAT_REDUCE(acc, o, C2)
  }
  FLUSH_STATS(C2, partial)
}

/* ---- bn2 params (folded) + bn2+relu + conv3 (32->64) in-place ---- */
__global__ __launch_bounds__(256, 2) void k_conv3(const float* __restrict__ w3,
                                                  const float* __restrict__ b3,
                                                  const float* __restrict__ p2,
                                                  const float* __restrict__ g2,
                                                  const float* __restrict__ be2,
                                                  float* y,
                                                  float* __restrict__ partial) {
  __shared__ float red[2 * C3][4];
  __shared__ float tot[2 * C2];
  __shared__ float pl[2 * C2];
  const int tid = threadIdx.x;
  const int w = tid >> 6, lane = tid & 63;
  BN_PARAMS(C2, p2, g2, be2)
  const int m = blockIdx.x * 256 + tid;
  const int b = m >> 16;
  const int r = m & (RTOT - 1);
  float* yb = y + ((size_t)b * C3) * RTOT + r;
  float4 x0, x1, x2, x3, x4, x5, x6, x7;
  LDBN4(x0, 0)  LDBN4(x1, 4)  LDBN4(x2, 8)  LDBN4(x3, 12)
  LDBN4(x4, 16) LDBN4(x5, 20) LDBN4(x6, 24) LDBN4(x7, 28)
#pragma unroll 4
  for (int o = 0; o < C3; o++) {
    const float* wr = w3 + o * C2;
    float acc = b3[o];
    FMA4(wr, 0, x0, acc)
    FMA4(wr, 4, x1, acc)
    FMA4(wr, 8, x2, acc)
    FMA4(wr, 12, x3, acc)
    FMA4(wr, 16, x4, acc)
    FMA4(wr, 20, x5, acc)
    FMA4(wr, 24, x6, acc)
    FMA4(wr, 28, x7, acc)
    yb[(size_t)o * RTOT] = acc;                         /* raw pre-BN */
    STAT_REDUCE(acc, o, C3)
  }
  FLUSH_STATS(C3, partial)
}

/* ---- finalize BN params for layer 3 ---- */
__global__ void k_params(const float* __restrict__ partial,
                         const float* __restrict__ gamma,
                         const float* __restrict__ beta,
                         float* __restrict__ params, int C) {
  __shared__ float tot[2 * C3];
  const int t = threadIdx.x;                 /* blockDim == 2C */
  float v = 0.f;
#pragma unroll 1
  for (int sl = 0; sl < NSLOT; ++sl) v += partial[sl * 2 * C + t];
  tot[t] = v;
  __syncthreads();
  if (t < C) {
    const float inv = 1.0f / (float)MTOT;
    const float mean = tot[t] * inv;
    const float ex2 = tot[C + t] * inv;
    const float var = ex2 - mean * mean;
    const float sc = gamma[t] * rsqrtf(var + EPSBN);
    params[t] = sc;
    params[C + t] = beta[t] - mean * sc;
  }
}

/* ---- bn3 + relu + validity mask, in-place on d_out ---- */
__global__ __launch_bounds__(256) void k_final(float* __restrict__ out,
                                               const float* __restrict__ par,
                                               const int* __restrict__ valid) {
  const int t = blockIdx.x * 256 + threadIdx.x;   /* float4 per thread */
  const size_t e = (size_t)t * 4;
  const int b = t >> 20;
  const int o = (t >> 14) & 63;
  const int s = (t & 16383) >> 3;
  const float sc = par[o], sh = par[C3 + o];
  const float m = valid[(b << 11) + s] ? 1.f : 0.f;
  float4 v = *(float4*)(out + e);
  v.x = fmaxf(fmaf(v.x, sc, sh), 0.f) * m;
  v.y = fmaxf(fmaf(v.y, sc, sh), 0.f) * m;
  v.z = fmaxf(fmaf(v.z, sc, sh), 0.f) * m;
  v.w = fmaxf(fmaf(v.w, sc, sh), 0.f) * m;
  *(float4*)(out + e) = v;
}

extern "C" void kernel_launch(void* const* d_in, const int* in_sizes, int n_in,
                              void* d_out, int out_size, void* d_ws, size_t ws_size,
                              hipStream_t stream) {
  const float* pc    = (const float*)d_in[0];
  const float* feat  = (const float*)d_in[1];
  const float* newpc = (const float*)d_in[2];
  const float* w1 = (const float*)d_in[3];
  const float* b1 = (const float*)d_in[4];
  const float* g1 = (const float*)d_in[5];
  const float* be1 = (const float*)d_in[6];
  const float* w2 = (const float*)d_in[7];
  const float* b2 = (const float*)d_in[8];
  const float* g2 = (const float*)d_in[9];
  const float* be2 = (const float*)d_in[10];
  const float* w3 = (const float*)d_in[11];
  const float* b3 = (const float*)d_in[12];
  const float* g3 = (const float*)d_in[13];
  const float* be3 = (const float*)d_in[14];

  float* ws = (float*)d_ws;
  float* gbuf  = ws + OFF_G;
  int*   idx   = (int*)(ws + OFF_IDX);
  int*   valid = (int*)(ws + OFF_VALID);
  float* p1 = ws + OFF_P1;
  float* p2 = ws + OFF_P2;
  float* p3 = ws + OFF_P3;
  float* par3 = ws + OFF_PAR3;
  float* out = (float*)d_out;

  k_pack<<<dim3(128), dim3(256), 0, stream>>>(pc, feat, gbuf, p1);
  k_ballquery<<<dim3(2048), dim3(256), 0, stream>>>(pc, newpc, idx, valid);
  k_conv1<<<dim3(1024), dim3(256), 0, stream>>>(gbuf, idx, newpc, w1, b1, out, p1);
  k_conv2<<<dim3(1024), dim3(256), 0, stream>>>(w2, b2, p1, g1, be1, out, p2);
  k_conv3<<<dim3(1024), dim3(256), 0, stream>>>(w3, b3, p2, g2, be2, out, p3);
  k_params<<<dim3(1), dim3(2 * C3), 0, stream>>>(p3, g3, be3, par3, C3);
  k_final<<<dim3(16384), dim3(256), 0, stream>>>(out, par3, valid);
}